// Round 2
// baseline (336.642 us; speedup 1.0000x reference)
//
#include <hip/hip_runtime.h>

#define B_   64
#define E_   1024
#define N_   512
#define D_   64
#define HID_ 128
#define T_   5

typedef __bf16 bf16x8 __attribute__((ext_vector_type(8)));
typedef float f32x4 __attribute__((ext_vector_type(4)));

__device__ __forceinline__ unsigned short f2bu(float f) {
    union { float f; unsigned int u; } v; v.f = f;
    unsigned int r = (v.u + 0x7fffu + ((v.u >> 16) & 1u)) >> 16;  // RNE
    return (unsigned short)r;
}

__device__ __forceinline__ unsigned int pack2(float lo, float hi) {
    union { __bf16 b[2]; unsigned int u; } v;
    v.b[0] = (__bf16)lo; v.b[1] = (__bf16)hi;   // RNE
    return v.u;
}

__device__ __forceinline__ uint4 cvt8(float4 a, float4 b) {
    union { __bf16 h[8]; uint4 u; } v;
    v.h[0] = (__bf16)a.x; v.h[1] = (__bf16)a.y; v.h[2] = (__bf16)a.z; v.h[3] = (__bf16)a.w;
    v.h[4] = (__bf16)b.x; v.h[5] = (__bf16)b.y; v.h[6] = (__bf16)b.z; v.h[7] = (__bf16)b.w;
    return v.u;
}

#define MFMA16(a, b, c) __builtin_amdgcn_mfma_f32_16x16x32_bf16((a), (b), (c), 0, 0, 0)

// ---------------------------------------------------------------------------
// Prep: W1[t][d][h] -> W1T[t][h][d] bf16 ; W2[t][h][d] -> W2T[t][d][h] bf16
// ---------------------------------------------------------------------------
__global__ __launch_bounds__(256) void k_prep_w(const float* __restrict__ W1,
                                                const float* __restrict__ W2,
                                                unsigned short* __restrict__ W1T,
                                                unsigned short* __restrict__ W2T) {
    int idx = blockIdx.x * 256 + threadIdx.x;
    if (idx < T_ * HID_ * D_) {
        int t = idx / (HID_ * D_), rem = idx % (HID_ * D_);
        int h = rem / D_, d = rem % D_;
        W1T[idx] = f2bu(W1[(t * D_ + d) * HID_ + h]);
    } else {
        int j = idx - T_ * HID_ * D_;
        int t = j / (D_ * HID_), rem = j % (D_ * HID_);
        int d = rem / HID_, h = rem % HID_;
        W2T[j] = f2bu(W2[(t * HID_ + h) * D_ + d]);
    }
}

// ---------------------------------------------------------------------------
// Prep: ori[b][n][d] -> oriT[b][d][n] bf16, and out[b][n][64+d] = ori (fp32)
// ---------------------------------------------------------------------------
__global__ __launch_bounds__(256) void k_ori_prep(const float* __restrict__ ori,
                                                  float* __restrict__ out,
                                                  unsigned short* __restrict__ oriT) {
    int b = blockIdx.y, n0 = blockIdx.x * 64;
    __shared__ float tl[64 * 65];
    int tid = threadIdx.x;
    int dl = tid & 63;
    #pragma unroll 4
    for (int p = 0; p < 16; ++p) {
        int nn = p * 4 + (tid >> 6);
        float v = ori[(size_t)(b * N_ + n0 + nn) * D_ + dl];
        out[(size_t)(b * N_ + n0 + nn) * 128 + 64 + dl] = v;
        tl[dl * 65 + nn] = v;
    }
    __syncthreads();
    #pragma unroll 4
    for (int p = 0; p < 16; ++p) {
        int dd = p * 4 + (tid >> 6);
        oriT[(size_t)(b * D_ + dd) * N_ + n0 + dl] = f2bu(tl[dd * 65 + dl]);
    }
}

// ---------------------------------------------------------------------------
// Fused K1+K2, v3:
//   Phase 1: ping-pong (1 barrier/step), unpadded XOR-swizzled 64x64 tiles.
//   Phase 2: ZERO barriers. All LDS deps are intra-wave (a_sh rows and the
//     per-wave h strip are wave-own); W1T/W2T MFMA B-fragments are loaded
//     directly from global (L2-resident, identical bytes to the staged copy).
//   No register weight prefetch (R1 spill lesson). LDS 37888 B -> 4 blocks/CU.
//   Barriers: 36 -> 9.
// ---------------------------------------------------------------------------
__global__ __launch_bounds__(256) void k_edge_mlp(const float* __restrict__ H,
                                                  const unsigned short* __restrict__ oriT,
                                                  const float* __restrict__ ed,
                                                  const float* __restrict__ b1,
                                                  const float* __restrict__ b2,
                                                  const unsigned short* __restrict__ W1T,
                                                  const unsigned short* __restrict__ W2T,
                                                  unsigned short* __restrict__ efT) {
    int bx = blockIdx.x;
    int b = bx >> 4, e0 = (bx & 15) * 64;
    // X (shorts): phase1 aA0[0,4096) bB0[4096,8192) aA1[8192,12288) bB1[12288,16384)
    //             phase2 a_sh[0,4096) ; per-wave h strip [4096 + w*2048, +2048)
    __shared__ __align__(16) unsigned short X[16384];
    __shared__ float wd_sh[320];
    __shared__ float b1_sh[640];
    __shared__ float b2_sh[320];
    int tid = threadIdx.x, w = tid >> 6, l = tid & 63, q = l >> 4, c = l & 15;
    int rs = tid >> 3, sgs = tid & 7;
    int swsl = (sgs ^ (rs & 7)) * 8;          // swizzled 8-elem slot for staging

    for (int u = tid; u < 320; u += 256) wd_sh[u] = ed[((size_t)b * E_ + e0) * T_ + u];
    for (int u = tid; u < 640; u += 256) b1_sh[u] = b1[u];
    for (int u = tid; u < 320; u += 256) b2_sh[u] = b2[u];

    const f32x4 zero = {0.f, 0.f, 0.f, 0.f};

    // ---- Phase 1: edges tile GEMM (M=64 e, N=64 d, K=512 n, BK=64) ----
    f32x4 acc1[4];
    #pragma unroll
    for (int fn = 0; fn < 4; ++fn) acc1[fn] = zero;

    const float* Hb = &H[((size_t)b * E_ + e0) * N_];
    const unsigned short* Ob = &oriT[(size_t)b * D_ * N_];

    float4 f00, f01, f10, f11;
    uint4 ob0, ob1;
    {   // prologue: ks=0 loads
        const float* s0 = Hb + (size_t)rs * N_ + sgs * 8;
        const float* s1 = Hb + (size_t)(rs + 32) * N_ + sgs * 8;
        f00 = *(const float4*)&s0[0]; f01 = *(const float4*)&s0[4];
        f10 = *(const float4*)&s1[0]; f11 = *(const float4*)&s1[4];
        ob0 = *(const uint4*)&Ob[(size_t)rs * N_ + sgs * 8];
        ob1 = *(const uint4*)&Ob[(size_t)(rs + 32) * N_ + sgs * 8];
    }
    {   // write buf0 (swizzled)
        unsigned short* aA = X;
        unsigned short* bB = X + 4096;
        *(uint4*)&aA[rs * 64 + swsl] = cvt8(f00, f01);
        *(uint4*)&aA[(rs + 32) * 64 + swsl] = cvt8(f10, f11);
        *(uint4*)&bB[rs * 64 + swsl] = ob0;
        *(uint4*)&bB[(rs + 32) * 64 + swsl] = ob1;
    }
    __syncthreads();

    for (int ks = 0; ks < 8; ++ks) {
        if (ks < 7) {  // issue next-step loads before compute
            int k0 = (ks + 1) * 64;
            const float* s0 = Hb + (size_t)rs * N_ + k0 + sgs * 8;
            const float* s1 = Hb + (size_t)(rs + 32) * N_ + k0 + sgs * 8;
            f00 = *(const float4*)&s0[0]; f01 = *(const float4*)&s0[4];
            f10 = *(const float4*)&s1[0]; f11 = *(const float4*)&s1[4];
            ob0 = *(const uint4*)&Ob[(size_t)rs * N_ + k0 + sgs * 8];
            ob1 = *(const uint4*)&Ob[(size_t)(rs + 32) * N_ + k0 + sgs * 8];
        }
        const unsigned short* aA = X + (ks & 1) * 8192;
        const unsigned short* bB = aA + 4096;
        #pragma unroll
        for (int hh = 0; hh < 2; ++hh) {
            int sl = ((hh * 4 + q) ^ (c & 7)) * 8;
            bf16x8 a0 = *(const bf16x8*)&aA[(w * 16 + c) * 64 + sl];
            #pragma unroll
            for (int fn = 0; fn < 4; ++fn) {
                bf16x8 bb = *(const bf16x8*)&bB[(fn * 16 + c) * 64 + sl];
                acc1[fn] = MFMA16(a0, bb, acc1[fn]);
            }
        }
        if (ks < 7) {
            unsigned short* aN = X + ((ks & 1) ^ 1) * 8192;
            unsigned short* bN = aN + 4096;
            *(uint4*)&aN[rs * 64 + swsl] = cvt8(f00, f01);
            *(uint4*)&aN[(rs + 32) * 64 + swsl] = cvt8(f10, f11);
            *(uint4*)&bN[rs * 64 + swsl] = ob0;
            *(uint4*)&bN[(rs + 32) * 64 + swsl] = ob1;
            __syncthreads();
        }
    }

    // a_sh write into aA0 region (safe: ks=7 reads only buf1), swizzled
    unsigned short* a_sh = X;
    #pragma unroll
    for (int fn = 0; fn < 4; ++fn)
        #pragma unroll
        for (int i = 0; i < 4; ++i) {
            int row = w * 16 + q * 4 + i;
            a_sh[row * 64 + ((fn * 16 + c) ^ ((row & 7) << 3))] = f2bu(acc1[fn][i]);
        }
    __syncthreads();  // ONLY barrier after phase 1: frees buf1/bB0 for h strips

    // A-fragments for GEMM1 (wave-own rows), loaded once
    bf16x8 afr[2];
    #pragma unroll
    for (int ks = 0; ks < 2; ++ks)
        afr[ks] = *(const bf16x8*)&a_sh[(w * 16 + c) * 64 + ((ks * 32 + q * 8) ^ ((c & 7) << 3))];

    unsigned short* hw = X + 4096 + w * 2048;  // per-wave [16][128] bf16 strip

    // ---- Phase 2: per-type MLP + mixture — barrier-free ----
    f32x4 y[4];
    #pragma unroll
    for (int fn = 0; fn < 4; ++fn) y[fn] = zero;

    for (int t = 0; t < T_; ++t) {
        const unsigned short* W1t = W1T + t * HID_ * D_;
        const unsigned short* W2t = W2T + t * D_ * HID_;
        f32x4 hc[8];
        #pragma unroll
        for (int fn = 0; fn < 8; ++fn) hc[fn] = zero;
        #pragma unroll
        for (int ks = 0; ks < 2; ++ks) {
            #pragma unroll
            for (int fn = 0; fn < 8; ++fn) {
                bf16x8 bb = *(const bf16x8*)&W1t[(fn * 16 + c) * D_ + ks * 32 + q * 8];
                hc[fn] = MFMA16(afr[ks], bb, hc[fn]);
            }
        }
        float wv[4];
        #pragma unroll
        for (int i = 0; i < 4; ++i) wv[i] = wd_sh[(w * 16 + q * 4 + i) * T_ + t];
        #pragma unroll
        for (int fn = 0; fn < 8; ++fn) {
            float b1v = b1_sh[t * HID_ + fn * 16 + c];
            #pragma unroll
            for (int i = 0; i < 4; ++i) {
                float v = fmaxf(hc[fn][i] + b1v, 0.0f) * wv[i];
                int row = q * 4 + i;
                hw[row * 128 + ((fn * 16 + c) ^ ((row & 7) << 3))] = f2bu(v);
            }
        }
        // intra-wave LDS write->read: compiler orders via lgkmcnt, no barrier
        #pragma unroll
        for (int ks = 0; ks < 4; ++ks) {
            bf16x8 a = *(const bf16x8*)&hw[c * 128 + ((ks * 32 + q * 8) ^ ((c & 7) << 3))];
            #pragma unroll
            for (int fn = 0; fn < 4; ++fn) {
                bf16x8 bb = *(const bf16x8*)&W2t[(fn * 16 + c) * HID_ + ks * 32 + q * 8];
                y[fn] = MFMA16(a, bb, y[fn]);
            }
        }
    }
    // epilogue: + sum_t w*b2, write efT[b][d][e] transposed (bf16 ushort4)
    #pragma unroll
    for (int fn = 0; fn < 4; ++fn) {
        int d = fn * 16 + c;
        ushort4 o;
        #pragma unroll
        for (int i = 0; i < 4; ++i) {
            int r = w * 16 + q * 4 + i;
            float s = y[fn][i];
            #pragma unroll
            for (int t = 0; t < T_; ++t) s += wd_sh[r * T_ + t] * b2_sh[t * D_ + d];
            ((unsigned short*)&o)[i] = f2bu(s);
        }
        *(ushort4*)&efT[((size_t)b * D_ + d) * E_ + e0 + w * 16 + q * 4] = o;
    }
}

// ---------------------------------------------------------------------------
// K3: out[b][n][d] = sum_e H[b][e][n] * ef[b][e][d] as outT tile.
// Ping-pong double-buffered K-loop (1 barrier/step) + XCD swizzle. Grid 512.
// ---------------------------------------------------------------------------
__global__ __launch_bounds__(256) void k_gemm_out(const float* __restrict__ H,
                                                  const unsigned short* __restrict__ efT,
                                                  float* __restrict__ out) {
    int bid = blockIdx.x;
    int swz = (bid & 7) * 64 + (bid >> 3);    // 512 % 8 == 0 -> bijective
    int b = swz >> 3, n0 = (swz & 7) * 64;
    __shared__ __align__(16) unsigned short aA[2][64 * 72];   // efT [d][e]
    __shared__ unsigned int bB32[2][64 * 33];                 // H^T [n][e/2] pair-packed
    int tid = threadIdx.x, w = tid >> 6, l = tid & 63, q = l >> 4, c = l & 15;
    int r2 = tid >> 3, cg = tid & 7;
    const f32x4 zero = {0.f, 0.f, 0.f, 0.f};
    f32x4 acc[4];
    #pragma unroll
    for (int fm = 0; fm < 4; ++fm) acc[fm] = zero;

    const unsigned short* Ab = &efT[(size_t)b * D_ * E_];
    const float* Hb = &H[(size_t)b * E_ * N_ + n0];

    uint4 ar0, ar1;
    float4 f0, f1, g0, g1;
    {   // prologue: ks=0 loads
        ar0 = *(const uint4*)&Ab[(size_t)r2 * E_ + cg * 8];
        ar1 = *(const uint4*)&Ab[(size_t)(r2 + 32) * E_ + cg * 8];
        const float* s0 = Hb + (size_t)(2 * r2) * N_ + cg * 8;
        const float* s1 = s0 + N_;
        f0 = *(const float4*)&s0[0]; f1 = *(const float4*)&s0[4];
        g0 = *(const float4*)&s1[0]; g1 = *(const float4*)&s1[4];
    }
    {   // write buf0
        *(uint4*)&aA[0][r2 * 72 + cg * 8] = ar0;
        *(uint4*)&aA[0][(r2 + 32) * 72 + cg * 8] = ar1;
        float r0a[8] = {f0.x, f0.y, f0.z, f0.w, f1.x, f1.y, f1.z, f1.w};
        float r1a[8] = {g0.x, g0.y, g0.z, g0.w, g1.x, g1.y, g1.z, g1.w};
        #pragma unroll
        for (int j = 0; j < 8; ++j)
            bB32[0][(cg * 8 + j) * 33 + r2] = pack2(r0a[j], r1a[j]);
    }
    __syncthreads();

    for (int ks = 0; ks < 16; ++ks) {
        if (ks < 15) {  // issue next-step loads before compute
            int k0 = (ks + 1) * 64;
            ar0 = *(const uint4*)&Ab[(size_t)r2 * E_ + k0 + cg * 8];
            ar1 = *(const uint4*)&Ab[(size_t)(r2 + 32) * E_ + k0 + cg * 8];
            const float* s0 = Hb + (size_t)(k0 + 2 * r2) * N_ + cg * 8;
            const float* s1 = s0 + N_;
            f0 = *(const float4*)&s0[0]; f1 = *(const float4*)&s0[4];
            g0 = *(const float4*)&s1[0]; g1 = *(const float4*)&s1[4];
        }
        int cur = ks & 1;
        #pragma unroll
        for (int hh = 0; hh < 2; ++hh) {
            union { unsigned int u[4]; bf16x8 v; } bb;
            #pragma unroll
            for (int i = 0; i < 4; ++i)
                bb.u[i] = bB32[cur][(w * 16 + c) * 33 + hh * 16 + q * 4 + i];
            #pragma unroll
            for (int fm = 0; fm < 4; ++fm) {
                bf16x8 afr = *(const bf16x8*)&aA[cur][(fm * 16 + c) * 72 + hh * 32 + q * 8];
                acc[fm] = MFMA16(afr, bb.v, acc[fm]);
            }
        }
        if (ks < 15) {
            int nxt = cur ^ 1;
            *(uint4*)&aA[nxt][r2 * 72 + cg * 8] = ar0;
            *(uint4*)&aA[nxt][(r2 + 32) * 72 + cg * 8] = ar1;
            float r0a[8] = {f0.x, f0.y, f0.z, f0.w, f1.x, f1.y, f1.z, f1.w};
            float r1a[8] = {g0.x, g0.y, g0.z, g0.w, g1.x, g1.y, g1.z, g1.w};
            #pragma unroll
            for (int j = 0; j < 8; ++j)
                bB32[nxt][(cg * 8 + j) * 33 + r2] = pack2(r0a[j], r1a[j]);
            __syncthreads();
        }
    }
    #pragma unroll
    for (int fm = 0; fm < 4; ++fm) {
        *(f32x4*)&out[((size_t)b * N_ + n0 + w * 16 + c) * 128 + fm * 16 + q * 4] = acc[fm];
    }
}

// ---------------------------------------------------------------------------
extern "C" void kernel_launch(void* const* d_in, const int* in_sizes, int n_in,
                              void* d_out, int out_size, void* d_ws, size_t ws_size,
                              hipStream_t stream) {
    const float* ed  = (const float*)d_in[0];  // [B,E,T]
    const float* H   = (const float*)d_in[1];  // [B,E,N]
    const float* ori = (const float*)d_in[2];  // [B,N,64]
    const float* W1  = (const float*)d_in[3];  // [T,64,128]
    const float* b1  = (const float*)d_in[4];  // [T,128]
    const float* W2  = (const float*)d_in[5];  // [T,128,64]
    const float* b2  = (const float*)d_in[6];  // [T,64]
    float* out = (float*)d_out;

    char* ws = (char*)d_ws;
    unsigned short* oriT = (unsigned short*)ws; ws += (size_t)B_ * D_ * N_ * 2;    // 4 MB
    unsigned short* W1T  = (unsigned short*)ws; ws += (size_t)T_ * HID_ * D_ * 2;
    unsigned short* W2T  = (unsigned short*)ws; ws += (size_t)T_ * D_ * HID_ * 2;
    unsigned short* efT  = (unsigned short*)ws; ws += (size_t)B_ * D_ * E_ * 2;    // 8 MB

    hipLaunchKernelGGL(k_prep_w, dim3(320), dim3(256), 0, stream, W1, W2, W1T, W2T);
    hipLaunchKernelGGL(k_ori_prep, dim3(8, 64), dim3(256), 0, stream, ori, out, oriT);
    hipLaunchKernelGGL(k_edge_mlp, dim3(1024), dim3(256), 0, stream,
                       H, oriT, ed, b1, b2, W1T, W2T, efT);
    hipLaunchKernelGGL(k_gemm_out, dim3(512), dim3(256), 0, stream, H, efT, out);
}

// Round 3
// 318.039 us; speedup vs baseline: 1.0585x; 1.0585x over previous
//
#include <hip/hip_runtime.h>

#define B_   64
#define E_   1024
#define N_   512
#define D_   64
#define HID_ 128
#define T_   5

typedef __bf16 bf16x8 __attribute__((ext_vector_type(8)));
typedef float f32x4 __attribute__((ext_vector_type(4)));

__device__ __forceinline__ unsigned short f2bu(float f) {
    union { float f; unsigned int u; } v; v.f = f;
    unsigned int r = (v.u + 0x7fffu + ((v.u >> 16) & 1u)) >> 16;  // RNE
    return (unsigned short)r;
}

__device__ __forceinline__ unsigned int pack2(float lo, float hi) {
    union { __bf16 b[2]; unsigned int u; } v;
    v.b[0] = (__bf16)lo; v.b[1] = (__bf16)hi;   // RNE
    return v.u;
}

__device__ __forceinline__ uint4 cvt8(float4 a, float4 b) {
    union { __bf16 h[8]; uint4 u; } v;
    v.h[0] = (__bf16)a.x; v.h[1] = (__bf16)a.y; v.h[2] = (__bf16)a.z; v.h[3] = (__bf16)a.w;
    v.h[4] = (__bf16)b.x; v.h[5] = (__bf16)b.y; v.h[6] = (__bf16)b.z; v.h[7] = (__bf16)b.w;
    return v.u;
}

#define MFMA16(a, b, c) __builtin_amdgcn_mfma_f32_16x16x32_bf16((a), (b), (c), 0, 0, 0)

// ---------------------------------------------------------------------------
// Prep: W1[t][d][h] -> W1T[t][h][d] bf16 ; W2[t][h][d] -> W2T[t][d][h] bf16
// ---------------------------------------------------------------------------
__global__ __launch_bounds__(256) void k_prep_w(const float* __restrict__ W1,
                                                const float* __restrict__ W2,
                                                unsigned short* __restrict__ W1T,
                                                unsigned short* __restrict__ W2T) {
    int idx = blockIdx.x * 256 + threadIdx.x;
    if (idx < T_ * HID_ * D_) {
        int t = idx / (HID_ * D_), rem = idx % (HID_ * D_);
        int h = rem / D_, d = rem % D_;
        W1T[idx] = f2bu(W1[(t * D_ + d) * HID_ + h]);
    } else {
        int j = idx - T_ * HID_ * D_;
        int t = j / (D_ * HID_), rem = j % (D_ * HID_);
        int d = rem / HID_, h = rem % HID_;
        W2T[j] = f2bu(W2[(t * HID_ + h) * D_ + d]);
    }
}

// ---------------------------------------------------------------------------
// Prep: ori[b][n][d] -> oriT[b][d][n] bf16, and out[b][n][64+d] = ori (fp32)
// ---------------------------------------------------------------------------
__global__ __launch_bounds__(256) void k_ori_prep(const float* __restrict__ ori,
                                                  float* __restrict__ out,
                                                  unsigned short* __restrict__ oriT) {
    int b = blockIdx.y, n0 = blockIdx.x * 64;
    __shared__ float tl[64 * 65];
    int tid = threadIdx.x;
    int dl = tid & 63;
    #pragma unroll 4
    for (int p = 0; p < 16; ++p) {
        int nn = p * 4 + (tid >> 6);
        float v = ori[(size_t)(b * N_ + n0 + nn) * D_ + dl];
        out[(size_t)(b * N_ + n0 + nn) * 128 + 64 + dl] = v;
        tl[dl * 65 + nn] = v;
    }
    __syncthreads();
    #pragma unroll 4
    for (int p = 0; p < 16; ++p) {
        int dd = p * 4 + (tid >> 6);
        oriT[(size_t)(b * D_ + dd) * N_ + n0 + dl] = f2bu(tl[dd * 65 + dl]);
    }
}

// ---------------------------------------------------------------------------
// Fused K1+K2, v4:
//   Phase 1: R2's ping-pong (1 barrier/step, XOR-swizzled, loads overlap
//     MFMA) — proven correct + spill-free at VGPR=72.
//   Phase 2: R0-verbatim LDS-staged weights (proven 88.6us) EXCEPT the weight
//     stage loads are issued into registers BEFORE the barrier (global reads
//     are WAR-safe; only the ds_write needs the barrier). #pragma unroll 1 on
//     the t-loop bounds the prefetch live range (R1 spill lesson).
//   LDS aliasing: phase-1 32KB ping-pong and phase-2 {a_sh,w_sh,h_sh} 45KB
//     share one region -> 50176 B total -> 3 blocks/CU (was 2).
//   Barriers: 36 -> 29.
// ---------------------------------------------------------------------------
__global__ __launch_bounds__(256) void k_edge_mlp(const float* __restrict__ H,
                                                  const unsigned short* __restrict__ oriT,
                                                  const float* __restrict__ ed,
                                                  const float* __restrict__ b1,
                                                  const float* __restrict__ b2,
                                                  const unsigned short* __restrict__ W1T,
                                                  const unsigned short* __restrict__ W2T,
                                                  unsigned short* __restrict__ efT) {
    int bx = blockIdx.x;
    int b = bx >> 4, e0 = (bx & 15) * 64;
    // X (short offsets):
    //   phase 1: buf0 aA[0,4096) bB[4096,8192); buf1 aA[8192,12288) bB[12288,16384)
    //   phase 2: a_sh[0,4608) w_sh[4608,13824) h_sh[13824,22528)
    __shared__ __align__(16) unsigned short X[22528];
    __shared__ float wd_sh[320];
    __shared__ float b1_sh[640];
    __shared__ float b2_sh[320];
    int tid = threadIdx.x, w = tid >> 6, l = tid & 63, q = l >> 4, c = l & 15;
    int rs = tid >> 3, sgs = tid & 7;
    int swsl = (sgs ^ (rs & 7)) * 8;          // swizzled 8-elem slot for staging

    for (int u = tid; u < 320; u += 256) wd_sh[u] = ed[((size_t)b * E_ + e0) * T_ + u];
    for (int u = tid; u < 640; u += 256) b1_sh[u] = b1[u];
    for (int u = tid; u < 320; u += 256) b2_sh[u] = b2[u];

    const f32x4 zero = {0.f, 0.f, 0.f, 0.f};

    // ---- Phase 1: edges tile GEMM (M=64 e, N=64 d, K=512 n, BK=64) ----
    f32x4 acc1[4];
    #pragma unroll
    for (int fn = 0; fn < 4; ++fn) acc1[fn] = zero;

    const float* Hb = &H[((size_t)b * E_ + e0) * N_];
    const unsigned short* Ob = &oriT[(size_t)b * D_ * N_];

    float4 f00, f01, f10, f11;
    uint4 ob0, ob1;
    {   // prologue: ks=0 loads
        const float* s0 = Hb + (size_t)rs * N_ + sgs * 8;
        const float* s1 = Hb + (size_t)(rs + 32) * N_ + sgs * 8;
        f00 = *(const float4*)&s0[0]; f01 = *(const float4*)&s0[4];
        f10 = *(const float4*)&s1[0]; f11 = *(const float4*)&s1[4];
        ob0 = *(const uint4*)&Ob[(size_t)rs * N_ + sgs * 8];
        ob1 = *(const uint4*)&Ob[(size_t)(rs + 32) * N_ + sgs * 8];
    }
    {   // write buf0 (swizzled)
        unsigned short* aA = X;
        unsigned short* bB = X + 4096;
        *(uint4*)&aA[rs * 64 + swsl] = cvt8(f00, f01);
        *(uint4*)&aA[(rs + 32) * 64 + swsl] = cvt8(f10, f11);
        *(uint4*)&bB[rs * 64 + swsl] = ob0;
        *(uint4*)&bB[(rs + 32) * 64 + swsl] = ob1;
    }
    __syncthreads();

    for (int ks = 0; ks < 8; ++ks) {
        if (ks < 7) {  // issue next-step loads before compute
            int k0 = (ks + 1) * 64;
            const float* s0 = Hb + (size_t)rs * N_ + k0 + sgs * 8;
            const float* s1 = Hb + (size_t)(rs + 32) * N_ + k0 + sgs * 8;
            f00 = *(const float4*)&s0[0]; f01 = *(const float4*)&s0[4];
            f10 = *(const float4*)&s1[0]; f11 = *(const float4*)&s1[4];
            ob0 = *(const uint4*)&Ob[(size_t)rs * N_ + k0 + sgs * 8];
            ob1 = *(const uint4*)&Ob[(size_t)(rs + 32) * N_ + k0 + sgs * 8];
        }
        const unsigned short* aA = X + (ks & 1) * 8192;
        const unsigned short* bB = aA + 4096;
        #pragma unroll
        for (int hh = 0; hh < 2; ++hh) {
            int sl = ((hh * 4 + q) ^ (c & 7)) * 8;
            bf16x8 a0 = *(const bf16x8*)&aA[(w * 16 + c) * 64 + sl];
            #pragma unroll
            for (int fn = 0; fn < 4; ++fn) {
                bf16x8 bb = *(const bf16x8*)&bB[(fn * 16 + c) * 64 + sl];
                acc1[fn] = MFMA16(a0, bb, acc1[fn]);
            }
        }
        if (ks < 7) {
            unsigned short* aN = X + ((ks & 1) ^ 1) * 8192;
            unsigned short* bN = aN + 4096;
            *(uint4*)&aN[rs * 64 + swsl] = cvt8(f00, f01);
            *(uint4*)&aN[(rs + 32) * 64 + swsl] = cvt8(f10, f11);
            *(uint4*)&bN[rs * 64 + swsl] = ob0;
            *(uint4*)&bN[(rs + 32) * 64 + swsl] = ob1;
            __syncthreads();
        }
    }

    // a_sh (72-padded) into buf0 region — safe: ks=7 MFMAs read only buf1
    unsigned short* a_sh = X;           // [0, 4608) shorts
    unsigned short* w_sh = X + 4608;    // [4608, 13824)
    unsigned short* h_sh = X + 13824;   // [13824, 22528)
    #pragma unroll
    for (int fn = 0; fn < 4; ++fn)
        #pragma unroll
        for (int i = 0; i < 4; ++i)
            a_sh[(w * 16 + q * 4 + i) * 72 + fn * 16 + c] = f2bu(acc1[fn][i]);
    // visibility via B0 barrier at top of t-loop

    // ---- Phase 2: per-type MLP + mixture (R0 structure, pre-barrier loads) ----
    f32x4 y[4];
    #pragma unroll
    for (int fn = 0; fn < 4; ++fn) y[fn] = zero;

    #pragma unroll 1
    for (int t = 0; t < T_; ++t) {
        // pre-load W1(t) into regs BEFORE the barrier (global read: WAR-safe)
        uint4 wr[4];
        #pragma unroll
        for (int p = 0; p < 4; ++p) {
            int u2 = p * 256 + tid;
            wr[p] = *(const uint4*)&W1T[((size_t)t * HID_ + (u2 >> 3)) * D_ + (u2 & 7) * 8];
        }
        __syncthreads();  // B0: w_sh free (prev GEMM2 done); a_sh/wd/b visible
        #pragma unroll
        for (int p = 0; p < 4; ++p) {
            int u2 = p * 256 + tid;
            *(uint4*)&w_sh[(u2 >> 3) * 72 + (u2 & 7) * 8] = wr[p];
        }
        __syncthreads();  // B1
        f32x4 hc[8];
        #pragma unroll
        for (int fn = 0; fn < 8; ++fn) hc[fn] = zero;
        #pragma unroll
        for (int ks = 0; ks < 2; ++ks) {
            bf16x8 a = *(const bf16x8*)&a_sh[(w * 16 + c) * 72 + ks * 32 + q * 8];
            #pragma unroll
            for (int fn = 0; fn < 8; ++fn) {
                bf16x8 bb = *(const bf16x8*)&w_sh[(fn * 16 + c) * 72 + ks * 32 + q * 8];
                hc[fn] = MFMA16(a, bb, hc[fn]);
            }
        }
        // pre-load W2(t) into regs (consumed after B2)
        #pragma unroll
        for (int p = 0; p < 4; ++p) {
            int u2 = p * 256 + tid;
            wr[p] = *(const uint4*)&W2T[((size_t)t * D_ + (u2 >> 4)) * HID_ + (u2 & 15) * 8];
        }
        float wv[4];
        #pragma unroll
        for (int i = 0; i < 4; ++i) wv[i] = wd_sh[(w * 16 + q * 4 + i) * T_ + t];
        #pragma unroll
        for (int fn = 0; fn < 8; ++fn) {
            float b1v = b1_sh[t * HID_ + fn * 16 + c];
            #pragma unroll
            for (int i = 0; i < 4; ++i) {
                float v = hc[fn][i] + b1v;
                v = fmaxf(v, 0.0f) * wv[i];
                h_sh[(w * 16 + q * 4 + i) * 136 + fn * 16 + c] = f2bu(v);
            }
        }
        __syncthreads();  // B2: GEMM1 w_sh reads + h_sh writes complete
        #pragma unroll
        for (int p = 0; p < 4; ++p) {
            int u2 = p * 256 + tid;
            *(uint4*)&w_sh[(u2 >> 4) * 136 + (u2 & 15) * 8] = wr[p];
        }
        __syncthreads();  // B3
        #pragma unroll
        for (int ks = 0; ks < 4; ++ks) {
            bf16x8 a = *(const bf16x8*)&h_sh[(w * 16 + c) * 136 + ks * 32 + q * 8];
            #pragma unroll
            for (int fn = 0; fn < 4; ++fn) {
                bf16x8 bb = *(const bf16x8*)&w_sh[(fn * 16 + c) * 136 + ks * 32 + q * 8];
                y[fn] = MFMA16(a, bb, y[fn]);
            }
        }
    }
    // epilogue: + sum_t w*b2, write efT[b][d][e] transposed (bf16 ushort4)
    #pragma unroll
    for (int fn = 0; fn < 4; ++fn) {
        int d = fn * 16 + c;
        ushort4 o;
        #pragma unroll
        for (int i = 0; i < 4; ++i) {
            int r = w * 16 + q * 4 + i;
            float s = y[fn][i];
            #pragma unroll
            for (int t = 0; t < T_; ++t) s += wd_sh[r * T_ + t] * b2_sh[t * D_ + d];
            ((unsigned short*)&o)[i] = f2bu(s);
        }
        *(ushort4*)&efT[((size_t)b * D_ + d) * E_ + e0 + w * 16 + q * 4] = o;
    }
}

// ---------------------------------------------------------------------------
// K3: out[b][n][d] = sum_e H[b][e][n] * ef[b][e][d] as outT tile.
// Ping-pong double-buffered K-loop (1 barrier/step) + XCD swizzle. Grid 512.
// ---------------------------------------------------------------------------
__global__ __launch_bounds__(256) void k_gemm_out(const float* __restrict__ H,
                                                  const unsigned short* __restrict__ efT,
                                                  float* __restrict__ out) {
    int bid = blockIdx.x;
    int swz = (bid & 7) * 64 + (bid >> 3);    // 512 % 8 == 0 -> bijective
    int b = swz >> 3, n0 = (swz & 7) * 64;
    __shared__ __align__(16) unsigned short aA[2][64 * 72];   // efT [d][e]
    __shared__ unsigned int bB32[2][64 * 33];                 // H^T [n][e/2] pair-packed
    int tid = threadIdx.x, w = tid >> 6, l = tid & 63, q = l >> 4, c = l & 15;
    int r2 = tid >> 3, cg = tid & 7;
    const f32x4 zero = {0.f, 0.f, 0.f, 0.f};
    f32x4 acc[4];
    #pragma unroll
    for (int fm = 0; fm < 4; ++fm) acc[fm] = zero;

    const unsigned short* Ab = &efT[(size_t)b * D_ * E_];
    const float* Hb = &H[(size_t)b * E_ * N_ + n0];

    uint4 ar0, ar1;
    float4 f0, f1, g0, g1;
    {   // prologue: ks=0 loads
        ar0 = *(const uint4*)&Ab[(size_t)r2 * E_ + cg * 8];
        ar1 = *(const uint4*)&Ab[(size_t)(r2 + 32) * E_ + cg * 8];
        const float* s0 = Hb + (size_t)(2 * r2) * N_ + cg * 8;
        const float* s1 = s0 + N_;
        f0 = *(const float4*)&s0[0]; f1 = *(const float4*)&s0[4];
        g0 = *(const float4*)&s1[0]; g1 = *(const float4*)&s1[4];
    }
    {   // write buf0
        *(uint4*)&aA[0][r2 * 72 + cg * 8] = ar0;
        *(uint4*)&aA[0][(r2 + 32) * 72 + cg * 8] = ar1;
        float r0a[8] = {f0.x, f0.y, f0.z, f0.w, f1.x, f1.y, f1.z, f1.w};
        float r1a[8] = {g0.x, g0.y, g0.z, g0.w, g1.x, g1.y, g1.z, g1.w};
        #pragma unroll
        for (int j = 0; j < 8; ++j)
            bB32[0][(cg * 8 + j) * 33 + r2] = pack2(r0a[j], r1a[j]);
    }
    __syncthreads();

    for (int ks = 0; ks < 16; ++ks) {
        if (ks < 15) {  // issue next-step loads before compute
            int k0 = (ks + 1) * 64;
            ar0 = *(const uint4*)&Ab[(size_t)r2 * E_ + k0 + cg * 8];
            ar1 = *(const uint4*)&Ab[(size_t)(r2 + 32) * E_ + k0 + cg * 8];
            const float* s0 = Hb + (size_t)(k0 + 2 * r2) * N_ + cg * 8;
            const float* s1 = s0 + N_;
            f0 = *(const float4*)&s0[0]; f1 = *(const float4*)&s0[4];
            g0 = *(const float4*)&s1[0]; g1 = *(const float4*)&s1[4];
        }
        int cur = ks & 1;
        #pragma unroll
        for (int hh = 0; hh < 2; ++hh) {
            union { unsigned int u[4]; bf16x8 v; } bb;
            #pragma unroll
            for (int i = 0; i < 4; ++i)
                bb.u[i] = bB32[cur][(w * 16 + c) * 33 + hh * 16 + q * 4 + i];
            #pragma unroll
            for (int fm = 0; fm < 4; ++fm) {
                bf16x8 afr = *(const bf16x8*)&aA[cur][(fm * 16 + c) * 72 + hh * 32 + q * 8];
                acc[fm] = MFMA16(afr, bb.v, acc[fm]);
            }
        }
        if (ks < 15) {
            int nxt = cur ^ 1;
            *(uint4*)&aA[nxt][r2 * 72 + cg * 8] = ar0;
            *(uint4*)&aA[nxt][(r2 + 32) * 72 + cg * 8] = ar1;
            float r0a[8] = {f0.x, f0.y, f0.z, f0.w, f1.x, f1.y, f1.z, f1.w};
            float r1a[8] = {g0.x, g0.y, g0.z, g0.w, g1.x, g1.y, g1.z, g1.w};
            #pragma unroll
            for (int j = 0; j < 8; ++j)
                bB32[nxt][(cg * 8 + j) * 33 + r2] = pack2(r0a[j], r1a[j]);
            __syncthreads();
        }
    }
    #pragma unroll
    for (int fm = 0; fm < 4; ++fm) {
        *(f32x4*)&out[((size_t)b * N_ + n0 + w * 16 + c) * 128 + fm * 16 + q * 4] = acc[fm];
    }
}

// ---------------------------------------------------------------------------
extern "C" void kernel_launch(void* const* d_in, const int* in_sizes, int n_in,
                              void* d_out, int out_size, void* d_ws, size_t ws_size,
                              hipStream_t stream) {
    const float* ed  = (const float*)d_in[0];  // [B,E,T]
    const float* H   = (const float*)d_in[1];  // [B,E,N]
    const float* ori = (const float*)d_in[2];  // [B,N,64]
    const float* W1  = (const float*)d_in[3];  // [T,64,128]
    const float* b1  = (const float*)d_in[4];  // [T,128]
    const float* W2  = (const float*)d_in[5];  // [T,128,64]
    const float* b2  = (const float*)d_in[6];  // [T,64]
    float* out = (float*)d_out;

    char* ws = (char*)d_ws;
    unsigned short* oriT = (unsigned short*)ws; ws += (size_t)B_ * D_ * N_ * 2;    // 4 MB
    unsigned short* W1T  = (unsigned short*)ws; ws += (size_t)T_ * HID_ * D_ * 2;
    unsigned short* W2T  = (unsigned short*)ws; ws += (size_t)T_ * D_ * HID_ * 2;
    unsigned short* efT  = (unsigned short*)ws; ws += (size_t)B_ * D_ * E_ * 2;    // 8 MB

    hipLaunchKernelGGL(k_prep_w, dim3(320), dim3(256), 0, stream, W1, W2, W1T, W2T);
    hipLaunchKernelGGL(k_ori_prep, dim3(8, 64), dim3(256), 0, stream, ori, out, oriT);
    hipLaunchKernelGGL(k_edge_mlp, dim3(1024), dim3(256), 0, stream,
                       H, oriT, ed, b1, b2, W1T, W2T, efT);
    hipLaunchKernelGGL(k_gemm_out, dim3(512), dim3(256), 0, stream, H, efT, out);
}

// Round 4
// 267.198 us; speedup vs baseline: 1.2599x; 1.1903x over previous
//
#include <hip/hip_runtime.h>

#define B_   64
#define E_   1024
#define N_   512
#define D_   64
#define HID_ 128
#define T_   5

typedef __bf16 bf16x8 __attribute__((ext_vector_type(8)));
typedef float f32x4 __attribute__((ext_vector_type(4)));

__device__ __forceinline__ unsigned short f2bu(float f) {
    union { float f; unsigned int u; } v; v.f = f;
    unsigned int r = (v.u + 0x7fffu + ((v.u >> 16) & 1u)) >> 16;  // RNE
    return (unsigned short)r;
}

__device__ __forceinline__ unsigned int pack2(float lo, float hi) {
    union { __bf16 b[2]; unsigned int u; } v;
    v.b[0] = (__bf16)lo; v.b[1] = (__bf16)hi;   // RNE
    return v.u;
}

__device__ __forceinline__ uint4 cvt8(float4 a, float4 b) {
    union { __bf16 h[8]; uint4 u; } v;
    v.h[0] = (__bf16)a.x; v.h[1] = (__bf16)a.y; v.h[2] = (__bf16)a.z; v.h[3] = (__bf16)a.w;
    v.h[4] = (__bf16)b.x; v.h[5] = (__bf16)b.y; v.h[6] = (__bf16)b.z; v.h[7] = (__bf16)b.w;
    return v.u;
}

#define MFMA16(a, b, c) __builtin_amdgcn_mfma_f32_16x16x32_bf16((a), (b), (c), 0, 0, 0)

// ---------------------------------------------------------------------------
// Prep: W1[t][d][h] -> W1T[t][h][d] bf16 ; W2[t][h][d] -> W2T[t][d][h] bf16
// ---------------------------------------------------------------------------
__global__ __launch_bounds__(256) void k_prep_w(const float* __restrict__ W1,
                                                const float* __restrict__ W2,
                                                unsigned short* __restrict__ W1T,
                                                unsigned short* __restrict__ W2T) {
    int idx = blockIdx.x * 256 + threadIdx.x;
    if (idx < T_ * HID_ * D_) {
        int t = idx / (HID_ * D_), rem = idx % (HID_ * D_);
        int h = rem / D_, d = rem % D_;
        W1T[idx] = f2bu(W1[(t * D_ + d) * HID_ + h]);
    } else {
        int j = idx - T_ * HID_ * D_;
        int t = j / (D_ * HID_), rem = j % (D_ * HID_);
        int d = rem / HID_, h = rem % HID_;
        W2T[j] = f2bu(W2[(t * HID_ + h) * D_ + d]);
    }
}

// ---------------------------------------------------------------------------
// Prep: ori[b][n][d] -> oriT[b][d][n] bf16, and out[b][n][64+d] = ori (fp32)
// ---------------------------------------------------------------------------
__global__ __launch_bounds__(256) void k_ori_prep(const float* __restrict__ ori,
                                                  float* __restrict__ out,
                                                  unsigned short* __restrict__ oriT) {
    int b = blockIdx.y, n0 = blockIdx.x * 64;
    __shared__ float tl[64 * 65];
    int tid = threadIdx.x;
    int dl = tid & 63;
    #pragma unroll 4
    for (int p = 0; p < 16; ++p) {
        int nn = p * 4 + (tid >> 6);
        float v = ori[(size_t)(b * N_ + n0 + nn) * D_ + dl];
        out[(size_t)(b * N_ + n0 + nn) * 128 + 64 + dl] = v;
        tl[dl * 65 + nn] = v;
    }
    __syncthreads();
    #pragma unroll 4
    for (int p = 0; p < 16; ++p) {
        int dd = p * 4 + (tid >> 6);
        oriT[(size_t)(b * D_ + dd) * N_ + n0 + dl] = f2bu(tl[dd * 65 + dl]);
    }
}

// ---------------------------------------------------------------------------
// Fused K1+K2, v5 = exact R0 structure with two surgical changes:
//   (a) W2 gets its own LDS buffer (w2_sh) -> the B2/B3 barriers that only
//       protected w_sh reuse are DELETED. h_sh round-trip was already
//       per-wave (write rows w*16+q*4+i, read rows w*16+c) -> intra-wave
//       DS ordering suffices (validated by R2's passing run). W1+W2 staged
//       together in ONE batched interval. Phase-2 intervals: 20 -> 10.
//   (b) phase-1 {aA,bB} alias the phase-2 {w1_sh,w2_sh} region (phase-1
//       reads end at its trailing barrier, before any weight write).
//       Total LDS 67584 <= R0's 68608 -> same 2 blocks/CU.
//   Everything else (phase-1 staging, fragment layouts, quantization
//   points, epilogue) is R0-verbatim. No register staging, no pragmas.
// ---------------------------------------------------------------------------
__global__ __launch_bounds__(256) void k_edge_mlp(const float* __restrict__ H,
                                                  const unsigned short* __restrict__ oriT,
                                                  const float* __restrict__ ed,
                                                  const float* __restrict__ b1,
                                                  const float* __restrict__ b2,
                                                  const unsigned short* __restrict__ W1T,
                                                  const unsigned short* __restrict__ W2T,
                                                  unsigned short* __restrict__ efT) {
    int bx = blockIdx.x;
    int b = bx >> 4, e0 = (bx & 15) * 64;
    // X (short offsets), 17920 shorts = 35840 B:
    //   phase 1: aA = X[0,4608)  bB = X[4608,9216)       (64x72 each)
    //   phase 2: w1_sh = X[0,9216) (128x72)  w2_sh = X[9216,17920) (64x136)
    __shared__ __align__(16) unsigned short X[17920];
    __shared__ __align__(16) unsigned short a_sh[64 * 72];   // edges tile [r][d]
    __shared__ __align__(16) unsigned short h_sh[64 * 136];  // per-wave strips
    __shared__ float wd_sh[320];
    __shared__ float b1_sh[640];
    __shared__ float b2_sh[320];
    int tid = threadIdx.x, w = tid >> 6, l = tid & 63, q = l >> 4, c = l & 15;

    // small staging (visible by first barrier below)
    for (int u = tid; u < 320; u += 256) wd_sh[u] = ed[((size_t)b * E_ + e0) * T_ + u];
    for (int u = tid; u < 640; u += 256) b1_sh[u] = b1[u];
    for (int u = tid; u < 320; u += 256) b2_sh[u] = b2[u];

    const f32x4 zero = {0.f, 0.f, 0.f, 0.f};

    // ---- Phase 1: edges tile GEMM (M=64 e-rows, N=64 d, K=512 n, BK=64) ----
    // R0-verbatim: 2 barriers per K-step.
    unsigned short* aA = X;
    unsigned short* bB = X + 4608;
    f32x4 acc1[4];
    #pragma unroll
    for (int fn = 0; fn < 4; ++fn) acc1[fn] = zero;

    for (int ks = 0; ks < 8; ++ks) {
        int k0 = ks * 64;
        // stage A: 64 e-rows x 64 floats of H -> bf16 (packed cvt)
        #pragma unroll
        for (int p = 0; p < 2; ++p) {
            int u = p * 256 + tid, r = u >> 3, sg = u & 7;
            const float* s = &H[((size_t)b * E_ + e0 + r) * N_ + k0 + sg * 8];
            float4 f0 = *(const float4*)&s[0];
            float4 f1 = *(const float4*)&s[4];
            *(uint4*)&aA[r * 72 + sg * 8] = cvt8(f0, f1);
        }
        // stage B: oriT rows (bf16, n-contig)
        #pragma unroll
        for (int p = 0; p < 2; ++p) {
            int u = p * 256 + tid, r = u >> 3, sg = u & 7;
            *(uint4*)&bB[r * 72 + sg * 8] =
                *(const uint4*)&oriT[((size_t)b * D_ + r) * N_ + k0 + sg * 8];
        }
        __syncthreads();
        #pragma unroll
        for (int h = 0; h < 2; ++h) {
            bf16x8 a0 = *(const bf16x8*)&aA[(w * 16 + c) * 72 + h * 32 + q * 8];
            #pragma unroll
            for (int fn = 0; fn < 4; ++fn) {
                bf16x8 bb = *(const bf16x8*)&bB[(fn * 16 + c) * 72 + h * 32 + q * 8];
                acc1[fn] = MFMA16(a0, bb, acc1[fn]);
            }
        }
        __syncthreads();   // trailing barrier: phase-1 reads of X complete
    }

    // C-layout -> a_sh[r][d] (bf16). Rows w*16+q*4+i are wave-own; the GEMM1
    // reads below (rows w*16+c) are the same wave's strip -> no barrier.
    #pragma unroll
    for (int fn = 0; fn < 4; ++fn)
        #pragma unroll
        for (int i = 0; i < 4; ++i)
            a_sh[(w * 16 + q * 4 + i) * 72 + fn * 16 + c] = f2bu(acc1[fn][i]);

    // A-fragments for GEMM1 (wave-own rows), loaded once
    bf16x8 afr[2];
    #pragma unroll
    for (int ks = 0; ks < 2; ++ks)
        afr[ks] = *(const bf16x8*)&a_sh[(w * 16 + c) * 72 + ks * 32 + q * 8];

    unsigned short* w1_sh = X;          // 128 x 72
    unsigned short* w2_sh = X + 9216;   // 64 x 136

    // ---- Phase 2: per-type MLP + mixture (2 barriers per t) ----
    f32x4 y[4];
    #pragma unroll
    for (int fn = 0; fn < 4; ++fn) y[fn] = zero;

    for (int t = 0; t < T_; ++t) {
        // batched stage of W1(t)+W2(t); 8 loads issue together.
        // safe for t=0: phase-1 reads of X ended at the trailing barrier.
        #pragma unroll
        for (int p = 0; p < 4; ++p) {
            int u2 = p * 256 + tid, hh = u2 >> 3, sg = u2 & 7;
            *(uint4*)&w1_sh[hh * 72 + sg * 8] =
                *(const uint4*)&W1T[((size_t)t * HID_ + hh) * D_ + sg * 8];
        }
        #pragma unroll
        for (int p = 0; p < 4; ++p) {
            int u2 = p * 256 + tid, dd = u2 >> 4, sg = u2 & 15;
            *(uint4*)&w2_sh[dd * 136 + sg * 8] =
                *(const uint4*)&W2T[((size_t)t * D_ + dd) * HID_ + sg * 8];
        }
        __syncthreads();  // S1: weights visible (also wd/b1/b2 at t=0)

        f32x4 hc[8];
        #pragma unroll
        for (int fn = 0; fn < 8; ++fn) hc[fn] = zero;
        #pragma unroll
        for (int ks = 0; ks < 2; ++ks) {
            #pragma unroll
            for (int fn = 0; fn < 8; ++fn) {
                bf16x8 bb = *(const bf16x8*)&w1_sh[(fn * 16 + c) * 72 + ks * 32 + q * 8];
                hc[fn] = MFMA16(afr[ks], bb, hc[fn]);
            }
        }
        float wv[4];
        #pragma unroll
        for (int i = 0; i < 4; ++i) wv[i] = wd_sh[(w * 16 + q * 4 + i) * T_ + t];
        #pragma unroll
        for (int fn = 0; fn < 8; ++fn) {
            float b1v = b1_sh[t * HID_ + fn * 16 + c];
            #pragma unroll
            for (int i = 0; i < 4; ++i) {
                float v = hc[fn][i] + b1v;
                v = fmaxf(v, 0.0f) * wv[i];
                h_sh[(w * 16 + q * 4 + i) * 136 + fn * 16 + c] = f2bu(v);
            }
        }
        // h_sh write rows (w*16+q*4+i) -> read rows (w*16+c): same wave,
        // in-order DS pipe + compiler lgkmcnt handles the dependency.
        #pragma unroll
        for (int ks = 0; ks < 4; ++ks) {
            bf16x8 a = *(const bf16x8*)&h_sh[(w * 16 + c) * 136 + ks * 32 + q * 8];
            #pragma unroll
            for (int fn = 0; fn < 4; ++fn) {
                bf16x8 bb = *(const bf16x8*)&w2_sh[(fn * 16 + c) * 136 + ks * 32 + q * 8];
                y[fn] = MFMA16(a, bb, y[fn]);
            }
        }
        if (t < T_ - 1) __syncthreads();  // S2: w1/w2 reads done before next stage
    }

    // epilogue: + sum_t w*b2, write efT[b][d][e] transposed (bf16 ushort4)
    #pragma unroll
    for (int fn = 0; fn < 4; ++fn) {
        int d = fn * 16 + c;
        ushort4 o;
        #pragma unroll
        for (int i = 0; i < 4; ++i) {
            int r = w * 16 + q * 4 + i;
            float s = y[fn][i];
            #pragma unroll
            for (int t = 0; t < T_; ++t) s += wd_sh[r * T_ + t] * b2_sh[t * D_ + d];
            ((unsigned short*)&o)[i] = f2bu(s);
        }
        *(ushort4*)&efT[((size_t)b * D_ + d) * E_ + e0 + w * 16 + q * 4] = o;
    }
}

// ---------------------------------------------------------------------------
// K3: out[b][n][d] = sum_e H[b][e][n] * ef[b][e][d] as outT tile.
// Ping-pong double-buffered K-loop (1 barrier/step) + XCD swizzle. Grid 512.
// (Unchanged from R1-R3; benched equal to R0's 2-barrier form.)
// ---------------------------------------------------------------------------
__global__ __launch_bounds__(256) void k_gemm_out(const float* __restrict__ H,
                                                  const unsigned short* __restrict__ efT,
                                                  float* __restrict__ out) {
    int bid = blockIdx.x;
    int swz = (bid & 7) * 64 + (bid >> 3);    // 512 % 8 == 0 -> bijective
    int b = swz >> 3, n0 = (swz & 7) * 64;
    __shared__ __align__(16) unsigned short aA[2][64 * 72];   // efT [d][e]
    __shared__ unsigned int bB32[2][64 * 33];                 // H^T [n][e/2] pair-packed
    int tid = threadIdx.x, w = tid >> 6, l = tid & 63, q = l >> 4, c = l & 15;
    int r2 = tid >> 3, cg = tid & 7;
    const f32x4 zero = {0.f, 0.f, 0.f, 0.f};
    f32x4 acc[4];
    #pragma unroll
    for (int fm = 0; fm < 4; ++fm) acc[fm] = zero;

    const unsigned short* Ab = &efT[(size_t)b * D_ * E_];
    const float* Hb = &H[(size_t)b * E_ * N_ + n0];

    uint4 ar0, ar1;
    float4 f0, f1, g0, g1;
    {   // prologue: ks=0 loads
        ar0 = *(const uint4*)&Ab[(size_t)r2 * E_ + cg * 8];
        ar1 = *(const uint4*)&Ab[(size_t)(r2 + 32) * E_ + cg * 8];
        const float* s0 = Hb + (size_t)(2 * r2) * N_ + cg * 8;
        const float* s1 = s0 + N_;
        f0 = *(const float4*)&s0[0]; f1 = *(const float4*)&s0[4];
        g0 = *(const float4*)&s1[0]; g1 = *(const float4*)&s1[4];
    }
    {   // write buf0
        *(uint4*)&aA[0][r2 * 72 + cg * 8] = ar0;
        *(uint4*)&aA[0][(r2 + 32) * 72 + cg * 8] = ar1;
        float r0a[8] = {f0.x, f0.y, f0.z, f0.w, f1.x, f1.y, f1.z, f1.w};
        float r1a[8] = {g0.x, g0.y, g0.z, g0.w, g1.x, g1.y, g1.z, g1.w};
        #pragma unroll
        for (int j = 0; j < 8; ++j)
            bB32[0][(cg * 8 + j) * 33 + r2] = pack2(r0a[j], r1a[j]);
    }
    __syncthreads();

    for (int ks = 0; ks < 16; ++ks) {
        if (ks < 15) {  // issue next-step loads before compute
            int k0 = (ks + 1) * 64;
            ar0 = *(const uint4*)&Ab[(size_t)r2 * E_ + k0 + cg * 8];
            ar1 = *(const uint4*)&Ab[(size_t)(r2 + 32) * E_ + k0 + cg * 8];
            const float* s0 = Hb + (size_t)(k0 + 2 * r2) * N_ + cg * 8;
            const float* s1 = s0 + N_;
            f0 = *(const float4*)&s0[0]; f1 = *(const float4*)&s0[4];
            g0 = *(const float4*)&s1[0]; g1 = *(const float4*)&s1[4];
        }
        int cur = ks & 1;
        #pragma unroll
        for (int hh = 0; hh < 2; ++hh) {
            union { unsigned int u[4]; bf16x8 v; } bb;
            #pragma unroll
            for (int i = 0; i < 4; ++i)
                bb.u[i] = bB32[cur][(w * 16 + c) * 33 + hh * 16 + q * 4 + i];
            #pragma unroll
            for (int fm = 0; fm < 4; ++fm) {
                bf16x8 afr = *(const bf16x8*)&aA[cur][(fm * 16 + c) * 72 + hh * 32 + q * 8];
                acc[fm] = MFMA16(afr, bb.v, acc[fm]);
            }
        }
        if (ks < 15) {
            int nxt = cur ^ 1;
            *(uint4*)&aA[nxt][r2 * 72 + cg * 8] = ar0;
            *(uint4*)&aA[nxt][(r2 + 32) * 72 + cg * 8] = ar1;
            float r0a[8] = {f0.x, f0.y, f0.z, f0.w, f1.x, f1.y, f1.z, f1.w};
            float r1a[8] = {g0.x, g0.y, g0.z, g0.w, g1.x, g1.y, g1.z, g1.w};
            #pragma unroll
            for (int j = 0; j < 8; ++j)
                bB32[nxt][(cg * 8 + j) * 33 + r2] = pack2(r0a[j], r1a[j]);
            __syncthreads();
        }
    }
    #pragma unroll
    for (int fm = 0; fm < 4; ++fm) {
        *(f32x4*)&out[((size_t)b * N_ + n0 + w * 16 + c) * 128 + fm * 16 + q * 4] = acc[fm];
    }
}

// ---------------------------------------------------------------------------
extern "C" void kernel_launch(void* const* d_in, const int* in_sizes, int n_in,
                              void* d_out, int out_size, void* d_ws, size_t ws_size,
                              hipStream_t stream) {
    const float* ed  = (const float*)d_in[0];  // [B,E,T]
    const float* H   = (const float*)d_in[1];  // [B,E,N]
    const float* ori = (const float*)d_in[2];  // [B,N,64]
    const float* W1  = (const float*)d_in[3];  // [T,64,128]
    const float* b1  = (const float*)d_in[4];  // [T,128]
    const float* W2  = (const float*)d_in[5];  // [T,128,64]
    const float* b2  = (const float*)d_in[6];  // [T,64]
    float* out = (float*)d_out;

    char* ws = (char*)d_ws;
    unsigned short* oriT = (unsigned short*)ws; ws += (size_t)B_ * D_ * N_ * 2;    // 4 MB
    unsigned short* W1T  = (unsigned short*)ws; ws += (size_t)T_ * HID_ * D_ * 2;
    unsigned short* W2T  = (unsigned short*)ws; ws += (size_t)T_ * D_ * HID_ * 2;
    unsigned short* efT  = (unsigned short*)ws; ws += (size_t)B_ * D_ * E_ * 2;    // 8 MB

    hipLaunchKernelGGL(k_prep_w, dim3(320), dim3(256), 0, stream, W1, W2, W1T, W2T);
    hipLaunchKernelGGL(k_ori_prep, dim3(8, 64), dim3(256), 0, stream, ori, out, oriT);
    hipLaunchKernelGGL(k_edge_mlp, dim3(1024), dim3(256), 0, stream,
                       H, oriT, ed, b1, b2, W1T, W2T, efT);
    hipLaunchKernelGGL(k_gemm_out, dim3(512), dim3(256), 0, stream, H, efT, out);
}